// Round 1
// baseline (518.409 us; speedup 1.0000x reference)
//
#include <hip/hip_runtime.h>

#define CIN   64
#define NOUT  128
#define IMH   128
#define IMW   128
#define NPTS  9
#define NB    4
#define HW    (IMH*IMW)          // 16384
#define ROWS  (IMH*NPTS)         // 1152
#define CHS   (ROWS*IMW)         // 147456
#define TOTAL ((size_t)NB*NOUT*CHS)  // 75497472

// ---------------- Kernel A: 3x3 SAME conv, C=64 -> 18 (offsets) ----------------
__global__ __launch_bounds__(256) void k_offset(const float* __restrict__ x,
                                                const float* __restrict__ pw,
                                                const float* __restrict__ pb,
                                                float* __restrict__ off) {
    // LDS weights, k-contiguous, padded to 20 per (c, dh, dw) for alignment
    __shared__ float wl[576 * 20];
    int tid = threadIdx.x;
    for (int t = tid; t < 18 * 576; t += 256) {
        int k = t / 576, cj = t % 576;       // pw layout [k][c][3][3]
        wl[cj * 20 + k] = pw[t];
    }
    __syncthreads();

    int gid = blockIdx.x * 256 + tid;
    int b = gid >> 14;
    int hw = gid & 16383;
    int h = hw >> 7;
    int w = hw & 127;

    float acc[18];
#pragma unroll
    for (int k = 0; k < 18; ++k) acc[k] = pb[k];

    const float* xb = x + (size_t)b * CIN * HW;
    for (int c = 0; c < CIN; ++c) {
        const float* xc = xb + c * HW;
#pragma unroll
        for (int dh = 0; dh < 3; ++dh) {
            int hh = h + dh - 1;
            if ((unsigned)hh >= 128u) continue;
#pragma unroll
            for (int dw = 0; dw < 3; ++dw) {
                int ww = w + dw - 1;
                if ((unsigned)ww >= 128u) continue;
                float xv = xc[hh * IMW + ww];
                const float* wr = &wl[(c * 9 + dh * 3 + dw) * 20];
#pragma unroll
                for (int k = 0; k < 18; ++k) acc[k] += wr[k] * xv;
            }
        }
    }
    float* ob = off + (size_t)b * 18 * HW + hw;
#pragma unroll
    for (int k = 0; k < 18; ++k) ob[k * HW] = acc[k];
}

// ---------------- Kernel Z: 1x1 conv, x[b][c][hw] -> z[b][hw][oc] ----------------
__global__ __launch_bounds__(256) void k_z(const float* __restrict__ x,
                                           const float* __restrict__ cw,
                                           float* __restrict__ z) {
    __shared__ float xs[64 * 128];   // [c][hw_local]
    __shared__ float wsm[64 * 128];  // [c][oc]
    int tid = threadIdx.x;
    int b   = blockIdx.x >> 7;
    int hw0 = (blockIdx.x & 127) << 7;

    const float* xb = x + (size_t)b * CIN * HW + hw0;
#pragma unroll
    for (int i = 0; i < 32; ++i) {
        int t = tid + i * 256;               // 8192 elements
        int c = t >> 7, l = t & 127;
        xs[t] = xb[c * HW + l];
    }
#pragma unroll
    for (int i = 0; i < 32; ++i) {
        int t = tid + i * 256;
        int oc = t & 127, c = t >> 7;        // cw layout [oc][c]
        wsm[c * 128 + oc] = cw[oc * 64 + c];
    }
    __syncthreads();

    int hw4  = (tid & 31) << 2;   // 4 consecutive hw
    int oc16 = (tid >> 5) << 4;   // 16 consecutive oc

    float acc[4][16];
#pragma unroll
    for (int j = 0; j < 4; ++j)
#pragma unroll
        for (int k = 0; k < 16; ++k) acc[j][k] = 0.f;

    for (int c = 0; c < 64; ++c) {
        float4 xv = *(const float4*)&xs[c * 128 + hw4];
        float xq[4] = {xv.x, xv.y, xv.z, xv.w};
        float wv[16];
        const float4* wrow = (const float4*)&wsm[c * 128 + oc16];
#pragma unroll
        for (int m = 0; m < 4; ++m) ((float4*)wv)[m] = wrow[m];
#pragma unroll
        for (int j = 0; j < 4; ++j)
#pragma unroll
            for (int k = 0; k < 16; ++k) acc[j][k] += xq[j] * wv[k];
    }

#pragma unroll
    for (int j = 0; j < 4; ++j) {
        size_t rowb = ((size_t)b * HW + hw0 + hw4 + j) * NOUT + oc16;
        float4* zp = (float4*)&z[rowb];
#pragma unroll
        for (int m = 0; m < 4; ++m)
            zp[m] = make_float4(acc[j][4*m], acc[j][4*m+1], acc[j][4*m+2], acc[j][4*m+3]);
    }
}

// ---------------- wave reduce ----------------
__device__ __forceinline__ float wred(float v) {
#pragma unroll
    for (int m = 32; m > 0; m >>= 1) v += __shfl_xor(v, m, 64);
    return v;
}

// ---------------- Kernel B: gather + combine + BN partial sums ----------------
__global__ __launch_bounds__(256) void k_main(const float* __restrict__ off,
                                              const float* __restrict__ z,
                                              float* __restrict__ out,
                                              float* __restrict__ gsum,
                                              float* __restrict__ gsq) {
    int bi = blockIdx.x;
    int n  = bi % 9;
    int t2 = bi / 9;
    int h  = t2 & 127;
    int b  = t2 >> 7;

    __shared__ float4 gS[128];
    __shared__ int4   iS[128];
    __shared__ float  lsum[128];
    __shared__ float  lsq[128];

    int tid = threadIdx.x;
    if (tid < 128) {
        lsum[tid] = 0.f; lsq[tid] = 0.f;
        int w = tid;
        const float* ob = off + ((size_t)b * 18 + n) * HW + h * IMW + w;
        float ox = ob[0];
        float oy = ob[9 * HW];
        float px = ox + (float)(n / 3) + (float)h;
        float py = oy + (float)(n % 3) + (float)w;
        float fX = floorf(px), fY = floorf(py);
        float fx = px - fX, fy = py - fY;
        int X = (int)fX, Y = (int)fY;
        float4 g;
        g.x = (1.f - fx) * (1.f - fy);   // lt
        g.y = fx * fy;                   // rb
        g.z = (1.f - fx) * fy;           // lb (X, Y+1)
        g.w = fx * (1.f - fy);           // rt (X+1, Y)
        int4 id;
        id.x = min(max(X * IMW + Y, 0), HW - 1);
        id.y = min(max((X + 1) * IMW + (Y + 1), 0), HW - 1);
        id.z = min(max(X * IMW + (Y + 1), 0), HW - 1);
        id.w = min(max((X + 1) * IMW + Y, 0), HW - 1);
        id.x *= NOUT; id.y *= NOUT; id.z *= NOUT; id.w *= NOUT;
        gS[w] = g; iS[w] = id;
    }
    __syncthreads();

    int w   = tid & 127;
    int obq = tid >> 7;     // 0 or 1
    float4 g = gS[w];
    int4  id = iS[w];
    const float* zb  = z + (size_t)b * HW * NOUT;
    const float* plt = zb + id.x;
    const float* prb = zb + id.y;
    const float* plb = zb + id.z;
    const float* prt = zb + id.w;
    int r = h * 9 + n;
    float* outw = out + (size_t)b * NOUT * CHS + (size_t)r * IMW + w;

#pragma unroll 2
    for (int i = 0; i < 16; ++i) {
        int oco = (obq + 2 * i) << 2;
        float4 vlt = *(const float4*)(plt + oco);
        float4 vrb = *(const float4*)(prb + oco);
        float4 vlb = *(const float4*)(plb + oco);
        float4 vrt = *(const float4*)(prt + oco);
        float4 a;
        a.x = g.x * vlt.x + g.y * vrb.x + g.z * vlb.x + g.w * vrt.x;
        a.y = g.x * vlt.y + g.y * vrb.y + g.z * vlb.y + g.w * vrt.y;
        a.z = g.x * vlt.z + g.y * vrb.z + g.z * vlb.z + g.w * vrt.z;
        a.w = g.x * vlt.w + g.y * vrb.w + g.z * vlb.w + g.w * vrt.w;

        float* o0 = outw + (size_t)oco * CHS;
        o0[0]             = a.x;
        o0[(size_t)CHS]   = a.y;
        o0[(size_t)2*CHS] = a.z;
        o0[(size_t)3*CHS] = a.w;

        float s0 = wred(a.x), s1 = wred(a.y), s2 = wred(a.z), s3 = wred(a.w);
        float q0 = wred(a.x * a.x), q1 = wred(a.y * a.y);
        float q2 = wred(a.z * a.z), q3 = wred(a.w * a.w);
        if ((tid & 63) == 0) {
            atomicAdd(&lsum[oco],     s0);
            atomicAdd(&lsum[oco + 1], s1);
            atomicAdd(&lsum[oco + 2], s2);
            atomicAdd(&lsum[oco + 3], s3);
            atomicAdd(&lsq[oco],      q0);
            atomicAdd(&lsq[oco + 1],  q1);
            atomicAdd(&lsq[oco + 2],  q2);
            atomicAdd(&lsq[oco + 3],  q3);
        }
    }
    __syncthreads();
    if (tid < 128)       atomicAdd(&gsum[tid],      lsum[tid]);
    else                 atomicAdd(&gsq[tid - 128], lsq[tid - 128]);
}

// ---------------- Kernel M: finalize BN stats -> scale/shift ----------------
__global__ void k_stats(const float* __restrict__ gsum, const float* __restrict__ gsq,
                        const float* __restrict__ gamma, const float* __restrict__ beta,
                        float* __restrict__ scale, float* __restrict__ shift) {
    int c = threadIdx.x;
    const float cnt = (float)(NB * ROWS * IMW);  // 589824
    float m = gsum[c] / cnt;
    float v = gsq[c] / cnt - m * m;
    float inv = rsqrtf(fmaxf(v, 0.f) + 1e-5f);
    float sc = inv * gamma[c];
    scale[c] = sc;
    shift[c] = beta[c] - m * sc;
}

// ---------------- Kernel C: in-place BN apply + SiLU ----------------
__global__ __launch_bounds__(256) void k_bnact(float* __restrict__ out,
                                               const float* __restrict__ scale,
                                               const float* __restrict__ shift) {
    const size_t total4 = TOTAL / 4;   // 18,874,368
    size_t stride = (size_t)gridDim.x * 256;
    for (size_t q = (size_t)blockIdx.x * 256 + threadIdx.x; q < total4; q += stride) {
        unsigned e = (unsigned)(q * 4);
        int oc = (int)((e / (unsigned)CHS) & 127u);
        float sc = scale[oc], sh = shift[oc];
        float4 v = ((float4*)out)[q];
        float t;
        t = v.x * sc + sh; v.x = t / (1.f + __expf(-t));
        t = v.y * sc + sh; v.y = t / (1.f + __expf(-t));
        t = v.z * sc + sh; v.z = t / (1.f + __expf(-t));
        t = v.w * sc + sh; v.w = t / (1.f + __expf(-t));
        ((float4*)out)[q] = v;
    }
}

extern "C" void kernel_launch(void* const* d_in, const int* in_sizes, int n_in,
                              void* d_out, int out_size, void* d_ws, size_t ws_size,
                              hipStream_t stream) {
    const float* x     = (const float*)d_in[0];
    const float* pw    = (const float*)d_in[1];
    const float* pb    = (const float*)d_in[2];
    const float* cw    = (const float*)d_in[3];
    const float* gamma = (const float*)d_in[4];
    const float* beta  = (const float*)d_in[5];
    // d_in[6] (attn_w), d_in[7] (attn_b): dead code in the reference — unused.

    float* out = (float*)d_out;
    float* ws  = (float*)d_ws;

    float* off   = ws;                                   // 4*18*16384      = 1,179,648 f
    float* z     = off + (size_t)NB * 18 * HW;           // 4*16384*128     = 8,388,608 f
    float* gsum  = z + (size_t)NB * HW * NOUT;           // 128 f
    float* gsq   = gsum + NOUT;                          // 128 f
    float* scale = gsq + NOUT;                           // 128 f
    float* shift = scale + NOUT;                         // 128 f

    hipLaunchKernelGGL(k_offset, dim3(256),  dim3(256), 0, stream, x, pw, pb, off);
    hipLaunchKernelGGL(k_z,      dim3(512),  dim3(256), 0, stream, x, cw, z);
    hipMemsetAsync(gsum, 0, 2 * NOUT * sizeof(float), stream);
    hipLaunchKernelGGL(k_main,   dim3(4608), dim3(256), 0, stream, off, z, out, gsum, gsq);
    hipLaunchKernelGGL(k_stats,  dim3(1),    dim3(128), 0, stream, gsum, gsq, gamma, beta, scale, shift);
    hipLaunchKernelGGL(k_bnact,  dim3(2048), dim3(256), 0, stream, out, scale, shift);
}

// Round 2
// 410.058 us; speedup vs baseline: 1.2642x; 1.2642x over previous
//
#include <hip/hip_runtime.h>

#define CIN   64
#define NOUT  128
#define IMH   128
#define IMW   128
#define NPTS  9
#define NB    4
#define HW    (IMH*IMW)          // 16384
#define ROWS  (IMH*NPTS)         // 1152
#define CHS   (ROWS*IMW)         // 147456
#define TOTAL ((size_t)NB*NOUT*CHS)  // 75497472

// ---------------- Kernel A: 3x3 SAME conv, C=64 -> 18 (offsets) ----------------
// 1024 blocks x 256 threads: 64 pixels/block, c-loop split across 4 groups of 16,
// LDS reduction at the end (4x the waves of the one-thread-per-pixel version).
__global__ __launch_bounds__(256) void k_offset(const float* __restrict__ x,
                                                const float* __restrict__ pw,
                                                const float* __restrict__ pb,
                                                float* __restrict__ off) {
    __shared__ float wl[576 * 19];        // [c*9+tap][k], stride 19
    __shared__ float red[3 * 64 * 19];    // partials from cg=1..3

    int tid = threadIdx.x;
    for (int t = tid; t < 18 * 576; t += 256) {
        int k = t / 576, cj = t % 576;    // pw layout [k][c][3][3]
        wl[cj * 19 + k] = pw[t];
    }
    __syncthreads();

    int cg = tid >> 6;        // 0..3 -> channel group
    int lp = tid & 63;        // pixel within block
    int gid = blockIdx.x * 64 + lp;
    int b = gid >> 14;
    int hw = gid & 16383;
    int h = hw >> 7;
    int w = hw & 127;

    float acc[18];
#pragma unroll
    for (int k = 0; k < 18; ++k) acc[k] = (cg == 0) ? pb[k] : 0.f;

    const float* xb = x + (size_t)b * CIN * HW;
    int c0 = cg * 16;
    for (int c = c0; c < c0 + 16; ++c) {
        const float* xc = xb + c * HW;
#pragma unroll
        for (int dh = 0; dh < 3; ++dh) {
            int hh = h + dh - 1;
            if ((unsigned)hh >= 128u) continue;
#pragma unroll
            for (int dw = 0; dw < 3; ++dw) {
                int ww = w + dw - 1;
                if ((unsigned)ww >= 128u) continue;
                float xv = xc[hh * IMW + ww];
                const float* wr = &wl[(c * 9 + dh * 3 + dw) * 19];
#pragma unroll
                for (int k = 0; k < 18; ++k) acc[k] += wr[k] * xv;
            }
        }
    }

    if (cg > 0) {
        float* rp = &red[((cg - 1) * 64 + lp) * 19];
#pragma unroll
        for (int k = 0; k < 18; ++k) rp[k] = acc[k];
    }
    __syncthreads();
    if (cg == 0) {
#pragma unroll
        for (int k = 0; k < 18; ++k)
            acc[k] += red[(0 * 64 + lp) * 19 + k] + red[(64 + lp) * 19 + k] + red[(128 + lp) * 19 + k];
        float* ob = off + (size_t)b * 18 * HW + hw;
#pragma unroll
        for (int k = 0; k < 18; ++k) ob[k * HW] = acc[k];
    }
}

// ---------------- Kernel Z: 1x1 conv, x[b][c][hw] -> z[b][hw][oc] ----------------
__global__ __launch_bounds__(256) void k_z(const float* __restrict__ x,
                                           const float* __restrict__ cw,
                                           float* __restrict__ z) {
    __shared__ float xs[64 * 128];   // [c][hw_local]
    __shared__ float wsm[64 * 128];  // [c][oc]
    int tid = threadIdx.x;
    int b   = blockIdx.x >> 7;
    int hw0 = (blockIdx.x & 127) << 7;

    const float* xb = x + (size_t)b * CIN * HW + hw0;
#pragma unroll
    for (int i = 0; i < 32; ++i) {
        int t = tid + i * 256;
        int c = t >> 7, l = t & 127;
        xs[t] = xb[c * HW + l];
    }
#pragma unroll
    for (int i = 0; i < 32; ++i) {
        int t = tid + i * 256;
        int oc = t & 127, c = t >> 7;        // cw layout [oc][c]
        wsm[c * 128 + oc] = cw[oc * 64 + c];
    }
    __syncthreads();

    int hw4  = (tid & 31) << 2;
    int oc16 = (tid >> 5) << 4;

    float acc[4][16];
#pragma unroll
    for (int j = 0; j < 4; ++j)
#pragma unroll
        for (int k = 0; k < 16; ++k) acc[j][k] = 0.f;

    for (int c = 0; c < 64; ++c) {
        float4 xv = *(const float4*)&xs[c * 128 + hw4];
        float xq[4] = {xv.x, xv.y, xv.z, xv.w};
        float wv[16];
        const float4* wrow = (const float4*)&wsm[c * 128 + oc16];
#pragma unroll
        for (int m = 0; m < 4; ++m) ((float4*)wv)[m] = wrow[m];
#pragma unroll
        for (int j = 0; j < 4; ++j)
#pragma unroll
            for (int k = 0; k < 16; ++k) acc[j][k] += xq[j] * wv[k];
    }

#pragma unroll
    for (int j = 0; j < 4; ++j) {
        size_t rowb = ((size_t)b * HW + hw0 + hw4 + j) * NOUT + oc16;
        float4* zp = (float4*)&z[rowb];
#pragma unroll
        for (int m = 0; m < 4; ++m)
            zp[m] = make_float4(acc[j][4*m], acc[j][4*m+1], acc[j][4*m+2], acc[j][4*m+3]);
    }
}

// ---------------- shared device helper: bilinear coords for one (b,h,n,w) ----------------
__device__ __forceinline__ void bilin_setup(const float* __restrict__ off,
                                            int b, int h, int n, int w,
                                            float4& g, int4& id) {
    const float* ob = off + ((size_t)b * 18 + n) * HW + h * IMW + w;
    float ox = ob[0];
    float oy = ob[9 * HW];
    float px = ox + (float)(n / 3) + (float)h;
    float py = oy + (float)(n % 3) + (float)w;
    float fX = floorf(px), fY = floorf(py);
    float fx = px - fX, fy = py - fY;
    int X = (int)fX, Y = (int)fY;
    g.x = (1.f - fx) * (1.f - fy);   // lt (X,   Y)
    g.y = fx * fy;                   // rb (X+1, Y+1)
    g.z = (1.f - fx) * fy;           // lb (X,   Y+1)
    g.w = fx * (1.f - fy);           // rt (X+1, Y)
    id.x = min(max(X * IMW + Y, 0), HW - 1) * NOUT;
    id.y = min(max((X + 1) * IMW + (Y + 1), 0), HW - 1) * NOUT;
    id.z = min(max(X * IMW + (Y + 1), 0), HW - 1) * NOUT;
    id.w = min(max((X + 1) * IMW + Y, 0), HW - 1) * NOUT;
}

// XCD-aware bijective swizzle: 4608 blocks = 8 XCDs x 576; each XCD gets one
// contiguous chunk (same b, 64-row h band -> z working set ~4.4MB ~ one L2).
__device__ __forceinline__ int swz_block() {
    return (blockIdx.x & 7) * 576 + (blockIdx.x >> 3);
}

// ---------------- Kernel S: gather pass 1 — BN sums only, channel-per-lane ----------------
__global__ __launch_bounds__(256) void k_sum(const float* __restrict__ off,
                                             const float* __restrict__ z,
                                             float* __restrict__ gsum,
                                             float* __restrict__ gsq) {
    int logical = swz_block();
    int n  = logical % 9;
    int t2 = logical / 9;
    int h  = t2 & 127;
    int b  = t2 >> 7;

    __shared__ float4 gS[128];
    __shared__ int4   iS[128];
    __shared__ float  lsum[128];
    __shared__ float  lsq[128];

    int tid = threadIdx.x;
    if (tid < 128) {
        lsum[tid] = 0.f; lsq[tid] = 0.f;
        float4 g; int4 id;
        bilin_setup(off, b, h, n, tid, g, id);
        gS[tid] = g; iS[tid] = id;
    }
    __syncthreads();

    int g32 = tid >> 5;              // 0..7: w sub-slot
    int c4  = (tid & 31) << 2;       // 4 consecutive channels
    const float* zb = z + (size_t)b * HW * NOUT + c4;

    float s0=0, s1=0, s2=0, s3=0, q0=0, q1=0, q2=0, q3=0;
#pragma unroll
    for (int wi = 0; wi < 16; ++wi) {
        int w = (wi << 3) + g32;
        float4 g = gS[w];
        int4  id = iS[w];
        float4 vlt = *(const float4*)(zb + id.x);
        float4 vrb = *(const float4*)(zb + id.y);
        float4 vlb = *(const float4*)(zb + id.z);
        float4 vrt = *(const float4*)(zb + id.w);
        float a0 = g.x*vlt.x + g.y*vrb.x + g.z*vlb.x + g.w*vrt.x;
        float a1 = g.x*vlt.y + g.y*vrb.y + g.z*vlb.y + g.w*vrt.y;
        float a2 = g.x*vlt.z + g.y*vrb.z + g.z*vlb.z + g.w*vrt.z;
        float a3 = g.x*vlt.w + g.y*vrb.w + g.z*vlb.w + g.w*vrt.w;
        s0 += a0; q0 += a0*a0;
        s1 += a1; q1 += a1*a1;
        s2 += a2; q2 += a2*a2;
        s3 += a3; q3 += a3*a3;
    }
    atomicAdd(&lsum[c4],     s0);
    atomicAdd(&lsum[c4 + 1], s1);
    atomicAdd(&lsum[c4 + 2], s2);
    atomicAdd(&lsum[c4 + 3], s3);
    atomicAdd(&lsq[c4],      q0);
    atomicAdd(&lsq[c4 + 1],  q1);
    atomicAdd(&lsq[c4 + 2],  q2);
    atomicAdd(&lsq[c4 + 3],  q3);
    __syncthreads();
    if (tid < 128)       atomicAdd(&gsum[tid],      lsum[tid]);
    else                 atomicAdd(&gsq[tid - 128], lsq[tid - 128]);
}

// ---------------- Kernel M: finalize BN stats -> scale/shift ----------------
__global__ void k_stats(const float* __restrict__ gsum, const float* __restrict__ gsq,
                        const float* __restrict__ gamma, const float* __restrict__ beta,
                        float* __restrict__ scale, float* __restrict__ shift) {
    int c = threadIdx.x;
    const float cnt = (float)(NB * ROWS * IMW);  // 589824
    float m = gsum[c] / cnt;
    float v = gsq[c] / cnt - m * m;
    float inv = rsqrtf(fmaxf(v, 0.f) + 1e-5f);
    float sc = inv * gamma[c];
    scale[c] = sc;
    shift[c] = beta[c] - m * sc;
}

// ---------------- Kernel B: gather pass 2 — combine + BN apply + SiLU + write ----------------
__global__ __launch_bounds__(256) void k_apply(const float* __restrict__ off,
                                               const float* __restrict__ z,
                                               const float* __restrict__ scale,
                                               const float* __restrict__ shift,
                                               float* __restrict__ out) {
    int logical = swz_block();
    int n  = logical % 9;
    int t2 = logical / 9;
    int h  = t2 & 127;
    int b  = t2 >> 7;

    __shared__ float4 gS[128];
    __shared__ int4   iS[128];
    __shared__ float  scS[128];
    __shared__ float  shS[128];

    int tid = threadIdx.x;
    if (tid < 128) {
        scS[tid] = scale[tid];
        shS[tid] = shift[tid];
        float4 g; int4 id;
        bilin_setup(off, b, h, n, tid, g, id);
        gS[tid] = g; iS[tid] = id;
    }
    __syncthreads();

    int w   = tid & 127;
    int obq = tid >> 7;     // 0 or 1
    float4 g = gS[w];
    int4  id = iS[w];
    const float* zb  = z + (size_t)b * HW * NOUT;
    const float* plt = zb + id.x;
    const float* prb = zb + id.y;
    const float* plb = zb + id.z;
    const float* prt = zb + id.w;
    int r = h * 9 + n;
    float* outw = out + (size_t)b * NOUT * CHS + (size_t)r * IMW + w;

#pragma unroll 4
    for (int i = 0; i < 16; ++i) {
        int oco = (obq + 2 * i) << 2;
        float4 vlt = *(const float4*)(plt + oco);
        float4 vrb = *(const float4*)(prb + oco);
        float4 vlb = *(const float4*)(plb + oco);
        float4 vrt = *(const float4*)(prt + oco);
        float4 sc = *(const float4*)&scS[oco];
        float4 sh = *(const float4*)&shS[oco];
        float t0 = (g.x*vlt.x + g.y*vrb.x + g.z*vlb.x + g.w*vrt.x) * sc.x + sh.x;
        float t1 = (g.x*vlt.y + g.y*vrb.y + g.z*vlb.y + g.w*vrt.y) * sc.y + sh.y;
        float t2v= (g.x*vlt.z + g.y*vrb.z + g.z*vlb.z + g.w*vrt.z) * sc.z + sh.z;
        float t3 = (g.x*vlt.w + g.y*vrb.w + g.z*vlb.w + g.w*vrt.w) * sc.w + sh.w;

        float* o0 = outw + (size_t)oco * CHS;
        o0[0]             = t0 / (1.f + __expf(-t0));
        o0[(size_t)CHS]   = t1 / (1.f + __expf(-t1));
        o0[(size_t)2*CHS] = t2v / (1.f + __expf(-t2v));
        o0[(size_t)3*CHS] = t3 / (1.f + __expf(-t3));
    }
}

extern "C" void kernel_launch(void* const* d_in, const int* in_sizes, int n_in,
                              void* d_out, int out_size, void* d_ws, size_t ws_size,
                              hipStream_t stream) {
    const float* x     = (const float*)d_in[0];
    const float* pw    = (const float*)d_in[1];
    const float* pb    = (const float*)d_in[2];
    const float* cw    = (const float*)d_in[3];
    const float* gamma = (const float*)d_in[4];
    const float* beta  = (const float*)d_in[5];
    // d_in[6]/d_in[7] (attn_w/attn_b): dead code in the reference — unused.

    float* out = (float*)d_out;
    float* ws  = (float*)d_ws;

    float* off   = ws;                                   // 4*18*16384
    float* z     = off + (size_t)NB * 18 * HW;           // 4*16384*128
    float* gsum  = z + (size_t)NB * HW * NOUT;           // 128
    float* gsq   = gsum + NOUT;                          // 128
    float* scale = gsq + NOUT;                           // 128
    float* shift = scale + NOUT;                         // 128

    hipLaunchKernelGGL(k_offset, dim3(1024), dim3(256), 0, stream, x, pw, pb, off);
    hipLaunchKernelGGL(k_z,      dim3(512),  dim3(256), 0, stream, x, cw, z);
    hipMemsetAsync(gsum, 0, 2 * NOUT * sizeof(float), stream);
    hipLaunchKernelGGL(k_sum,    dim3(4608), dim3(256), 0, stream, off, z, gsum, gsq);
    hipLaunchKernelGGL(k_stats,  dim3(1),    dim3(128), 0, stream, gsum, gsq, gamma, beta, scale, shift);
    hipLaunchKernelGGL(k_apply,  dim3(4608), dim3(256), 0, stream, off, z, scale, shift, out);
}

// Round 4
// 328.838 us; speedup vs baseline: 1.5765x; 1.2470x over previous
//
#include <hip/hip_runtime.h>

#define CIN   64
#define NOUT  128
#define IMH   128
#define IMW   128
#define NPTS  9
#define NB    4
#define HW    (IMH*IMW)          // 16384
#define ROWS  (IMH*NPTS)         // 1152
#define CHS   (ROWS*IMW)         // 147456
#define TOTAL ((size_t)NB*NOUT*CHS)  // 75497472

typedef float f32x4 __attribute__((ext_vector_type(4)));

// ---------------- Kernel A: 3x3 SAME conv, C=64 -> 18 (offsets) ----------------
__global__ __launch_bounds__(256) void k_offset(const float* __restrict__ x,
                                                const float* __restrict__ pw,
                                                const float* __restrict__ pb,
                                                float* __restrict__ off) {
    __shared__ float wl[576 * 19];        // [c*9+tap][k], stride 19
    __shared__ float red[3 * 64 * 19];    // partials from cg=1..3

    int tid = threadIdx.x;
    for (int t = tid; t < 18 * 576; t += 256) {
        int k = t / 576, cj = t % 576;    // pw layout [k][c][3][3]
        wl[cj * 19 + k] = pw[t];
    }
    __syncthreads();

    int cg = tid >> 6;        // 0..3 -> channel group
    int lp = tid & 63;        // pixel within block
    int gid = blockIdx.x * 64 + lp;
    int b = gid >> 14;
    int hw = gid & 16383;
    int h = hw >> 7;
    int w = hw & 127;

    float acc[18];
#pragma unroll
    for (int k = 0; k < 18; ++k) acc[k] = (cg == 0) ? pb[k] : 0.f;

    const float* xb = x + (size_t)b * CIN * HW;
    int c0 = cg * 16;
    for (int c = c0; c < c0 + 16; ++c) {
        const float* xc = xb + c * HW;
#pragma unroll
        for (int dh = 0; dh < 3; ++dh) {
            int hh = h + dh - 1;
            if ((unsigned)hh >= 128u) continue;
#pragma unroll
            for (int dw = 0; dw < 3; ++dw) {
                int ww = w + dw - 1;
                if ((unsigned)ww >= 128u) continue;
                float xv = xc[hh * IMW + ww];
                const float* wr = &wl[(c * 9 + dh * 3 + dw) * 19];
#pragma unroll
                for (int k = 0; k < 18; ++k) acc[k] += wr[k] * xv;
            }
        }
    }

    if (cg > 0) {
        float* rp = &red[((cg - 1) * 64 + lp) * 19];
#pragma unroll
        for (int k = 0; k < 18; ++k) rp[k] = acc[k];
    }
    __syncthreads();
    if (cg == 0) {
#pragma unroll
        for (int k = 0; k < 18; ++k)
            acc[k] += red[(0 * 64 + lp) * 19 + k] + red[(64 + lp) * 19 + k] + red[(128 + lp) * 19 + k];
        float* ob = off + (size_t)b * 18 * HW + hw;
#pragma unroll
        for (int k = 0; k < 18; ++k) ob[k * HW] = acc[k];
    }
}

// ---------------- Kernel Z: 1x1 conv, x[b][c][hw] -> z[b][hw][oc] ----------------
__global__ __launch_bounds__(256) void k_z(const float* __restrict__ x,
                                           const float* __restrict__ cw,
                                           float* __restrict__ z) {
    __shared__ float xs[64 * 128];   // [c][hw_local]
    __shared__ float wsm[64 * 128];  // [c][oc]
    int tid = threadIdx.x;
    int b   = blockIdx.x >> 7;
    int hw0 = (blockIdx.x & 127) << 7;

    const float* xb = x + (size_t)b * CIN * HW + hw0;
#pragma unroll
    for (int i = 0; i < 32; ++i) {
        int t = tid + i * 256;
        int c = t >> 7, l = t & 127;
        xs[t] = xb[c * HW + l];
    }
#pragma unroll
    for (int i = 0; i < 32; ++i) {
        int t = tid + i * 256;
        int oc = t & 127, c = t >> 7;        // cw layout [oc][c]
        wsm[c * 128 + oc] = cw[oc * 64 + c];
    }
    __syncthreads();

    int hw4  = (tid & 31) << 2;
    int oc16 = (tid >> 5) << 4;

    float acc[4][16];
#pragma unroll
    for (int j = 0; j < 4; ++j)
#pragma unroll
        for (int k = 0; k < 16; ++k) acc[j][k] = 0.f;

    for (int c = 0; c < 64; ++c) {
        float4 xv = *(const float4*)&xs[c * 128 + hw4];
        float xq[4] = {xv.x, xv.y, xv.z, xv.w};
        float wv[16];
        const float4* wrow = (const float4*)&wsm[c * 128 + oc16];
#pragma unroll
        for (int m = 0; m < 4; ++m) ((float4*)wv)[m] = wrow[m];
#pragma unroll
        for (int j = 0; j < 4; ++j)
#pragma unroll
            for (int k = 0; k < 16; ++k) acc[j][k] += xq[j] * wv[k];
    }

#pragma unroll
    for (int j = 0; j < 4; ++j) {
        size_t rowb = ((size_t)b * HW + hw0 + hw4 + j) * NOUT + oc16;
        float4* zp = (float4*)&z[rowb];
#pragma unroll
        for (int m = 0; m < 4; ++m)
            zp[m] = make_float4(acc[j][4*m], acc[j][4*m+1], acc[j][4*m+2], acc[j][4*m+3]);
    }
}

// ---------------- shared device helper: bilinear coords for one (b,h,n,w) ----------------
__device__ __forceinline__ void bilin_setup(const float* __restrict__ off,
                                            int b, int h, int n, int w,
                                            float4& g, int4& id) {
    const float* ob = off + ((size_t)b * 18 + n) * HW + h * IMW + w;
    float ox = ob[0];
    float oy = ob[9 * HW];
    float px = ox + (float)(n / 3) + (float)h;
    float py = oy + (float)(n % 3) + (float)w;
    float fX = floorf(px), fY = floorf(py);
    float fx = px - fX, fy = py - fY;
    int X = (int)fX, Y = (int)fY;
    g.x = (1.f - fx) * (1.f - fy);   // lt (X,   Y)
    g.y = fx * fy;                   // rb (X+1, Y+1)
    g.z = (1.f - fx) * fy;           // lb (X,   Y+1)
    g.w = fx * (1.f - fy);           // rt (X+1, Y)
    id.x = min(max(X * IMW + Y, 0), HW - 1) * NOUT;
    id.y = min(max((X + 1) * IMW + (Y + 1), 0), HW - 1) * NOUT;
    id.z = min(max(X * IMW + (Y + 1), 0), HW - 1) * NOUT;
    id.w = min(max((X + 1) * IMW + Y, 0), HW - 1) * NOUT;
}

// XCD-aware bijective swizzle: 4608 = 8 XCDs x 576 contiguous logical blocks.
__device__ __forceinline__ int swz_block() {
    return (blockIdx.x & 7) * 576 + (blockIdx.x >> 3);
}

// ---------------- Kernel S: gather pass 1 — BN sums, channel-per-lane, prefetched ----------------
__global__ __launch_bounds__(256) void k_sum(const float* __restrict__ off,
                                             const float* __restrict__ z,
                                             float* __restrict__ gsum,
                                             float* __restrict__ gsq) {
    int logical = swz_block();
    int n  = logical % 9;
    int t2 = logical / 9;
    int h  = t2 & 127;
    int b  = t2 >> 7;

    __shared__ float4 gS[128];
    __shared__ int4   iS[128];
    __shared__ float  lsum[128];
    __shared__ float  lsq[128];

    int tid = threadIdx.x;
    if (tid < 128) {
        lsum[tid] = 0.f; lsq[tid] = 0.f;
        float4 g; int4 id;
        bilin_setup(off, b, h, n, tid, g, id);
        gS[tid] = g; iS[tid] = id;
    }
    __syncthreads();

    int g32 = tid >> 5;              // 0..7: w sub-slot
    int c4  = (tid & 31) << 2;       // 4 consecutive channels
    const float* zb = z + (size_t)b * HW * NOUT + c4;

    float s0=0, s1=0, s2=0, s3=0, q0=0, q1=0, q2=0, q3=0;

    // depth-1 software prefetch: 8 float4 in flight per thread
    float4 plt, prb, plb, prt;
    {
        int4 id = iS[g32];
        plt = *(const float4*)(zb + id.x);
        prb = *(const float4*)(zb + id.y);
        plb = *(const float4*)(zb + id.z);
        prt = *(const float4*)(zb + id.w);
    }
#pragma unroll
    for (int wi = 0; wi < 16; ++wi) {
        float4 nlt, nrb, nlb, nrt;
        if (wi < 15) {
            int4 idn = iS[((wi + 1) << 3) + g32];
            nlt = *(const float4*)(zb + idn.x);
            nrb = *(const float4*)(zb + idn.y);
            nlb = *(const float4*)(zb + idn.z);
            nrt = *(const float4*)(zb + idn.w);
        }
        float4 g = gS[(wi << 3) + g32];
        float a0 = g.x*plt.x + g.y*prb.x + g.z*plb.x + g.w*prt.x;
        float a1 = g.x*plt.y + g.y*prb.y + g.z*plb.y + g.w*prt.y;
        float a2 = g.x*plt.z + g.y*prb.z + g.z*plb.z + g.w*prt.z;
        float a3 = g.x*plt.w + g.y*prb.w + g.z*plb.w + g.w*prt.w;
        s0 += a0; q0 += a0*a0;
        s1 += a1; q1 += a1*a1;
        s2 += a2; q2 += a2*a2;
        s3 += a3; q3 += a3*a3;
        plt = nlt; prb = nrb; plb = nlb; prt = nrt;
    }
    atomicAdd(&lsum[c4],     s0);
    atomicAdd(&lsum[c4 + 1], s1);
    atomicAdd(&lsum[c4 + 2], s2);
    atomicAdd(&lsum[c4 + 3], s3);
    atomicAdd(&lsq[c4],      q0);
    atomicAdd(&lsq[c4 + 1],  q1);
    atomicAdd(&lsq[c4 + 2],  q2);
    atomicAdd(&lsq[c4 + 3],  q3);
    __syncthreads();
    if (tid < 128)       atomicAdd(&gsum[tid],      lsum[tid]);
    else                 atomicAdd(&gsq[tid - 128], lsq[tid - 128]);
}

// ---------------- Kernel M: finalize BN stats -> scale/shift ----------------
__global__ void k_stats(const float* __restrict__ gsum, const float* __restrict__ gsq,
                        const float* __restrict__ gamma, const float* __restrict__ beta,
                        float* __restrict__ scale, float* __restrict__ shift) {
    int c = threadIdx.x;
    const float cnt = (float)(NB * ROWS * IMW);  // 589824
    float m = gsum[c] / cnt;
    float v = gsq[c] / cnt - m * m;
    float inv = rsqrtf(fmaxf(v, 0.f) + 1e-5f);
    float sc = inv * gamma[c];
    scale[c] = sc;
    shift[c] = beta[c] - m * sc;
}

// ---------------- Kernel B: gather pass 2 — channel-per-lane gather + LDS transpose
//                  + BN apply + SiLU + nontemporal coalesced stores ----------------
__global__ __launch_bounds__(256) void k_apply(const float* __restrict__ off,
                                               const float* __restrict__ z,
                                               const float* __restrict__ scale,
                                               const float* __restrict__ shift,
                                               float* __restrict__ out) {
    int logical = swz_block();
    int n  = logical % 9;
    int t2 = logical / 9;
    int h  = t2 & 127;
    int b  = t2 >> 7;

    __shared__ float4 gS[128];
    __shared__ int4   iS[128];
    __shared__ float  ybuf[32 * 132];   // [w_local][oc], stride 132

    int tid = threadIdx.x;
    if (tid < 128) {
        float4 g; int4 id;
        bilin_setup(off, b, h, n, tid, g, id);
        gS[tid] = g; iS[tid] = id;
    }
    __syncthreads();

    int ws = tid >> 5;               // 0..7: w sub-slot
    int c4 = (tid & 31) << 2;        // 4 consecutive channels
    float4 sc = *(const float4*)&scale[c4];
    float4 sh = *(const float4*)&shift[c4];
    const float* zb = z + (size_t)b * HW * NOUT + c4;
    int r = h * 9 + n;
    float* outr = out + (size_t)b * NOUT * CHS + (size_t)r * IMW;

    for (int chunk = 0; chunk < 4; ++chunk) {
        int w0 = chunk << 5;
        // gather: 32 w-pixels x 128 channels into LDS (post BN+SiLU)
#pragma unroll
        for (int jj = 0; jj < 4; ++jj) {
            int wl  = (jj << 3) + ws;
            int w   = w0 + wl;
            float4 g = gS[w];
            int4  id = iS[w];
            float4 vlt = *(const float4*)(zb + id.x);
            float4 vrb = *(const float4*)(zb + id.y);
            float4 vlb = *(const float4*)(zb + id.z);
            float4 vrt = *(const float4*)(zb + id.w);
            float t0 = (g.x*vlt.x + g.y*vrb.x + g.z*vlb.x + g.w*vrt.x) * sc.x + sh.x;
            float t1 = (g.x*vlt.y + g.y*vrb.y + g.z*vlb.y + g.w*vrt.y) * sc.y + sh.y;
            float t2v= (g.x*vlt.z + g.y*vrb.z + g.z*vlb.z + g.w*vrt.z) * sc.z + sh.z;
            float t3 = (g.x*vlt.w + g.y*vrb.w + g.z*vlb.w + g.w*vrt.w) * sc.w + sh.w;
            float4 y;
            y.x = t0 / (1.f + __expf(-t0));
            y.y = t1 / (1.f + __expf(-t1));
            y.z = t2v / (1.f + __expf(-t2v));
            y.w = t3 / (1.f + __expf(-t3));
            *(float4*)&ybuf[wl * 132 + c4] = y;
        }
        __syncthreads();
        // writeout: transpose from LDS, coalesced float4 over w, nontemporal
#pragma unroll
        for (int i = 0; i < 4; ++i) {
            int task = (i << 8) + tid;     // 0..1023
            int oc   = task >> 3;
            int w4   = (task & 7) << 2;
            f32x4 v;
            v.x = ybuf[(w4 + 0) * 132 + oc];
            v.y = ybuf[(w4 + 1) * 132 + oc];
            v.z = ybuf[(w4 + 2) * 132 + oc];
            v.w = ybuf[(w4 + 3) * 132 + oc];
            __builtin_nontemporal_store(v, (f32x4*)(outr + (size_t)oc * CHS + w0 + w4));
        }
        __syncthreads();
    }
}

extern "C" void kernel_launch(void* const* d_in, const int* in_sizes, int n_in,
                              void* d_out, int out_size, void* d_ws, size_t ws_size,
                              hipStream_t stream) {
    const float* x     = (const float*)d_in[0];
    const float* pw    = (const float*)d_in[1];
    const float* pb    = (const float*)d_in[2];
    const float* cw    = (const float*)d_in[3];
    const float* gamma = (const float*)d_in[4];
    const float* beta  = (const float*)d_in[5];
    // d_in[6]/d_in[7] (attn_w/attn_b): dead code in the reference — unused.

    float* out = (float*)d_out;
    float* ws  = (float*)d_ws;

    float* off   = ws;                                   // 4*18*16384
    float* z     = off + (size_t)NB * 18 * HW;           // 4*16384*128
    float* gsum  = z + (size_t)NB * HW * NOUT;           // 128
    float* gsq   = gsum + NOUT;                          // 128
    float* scale = gsq + NOUT;                           // 128
    float* shift = scale + NOUT;                         // 128

    hipLaunchKernelGGL(k_offset, dim3(1024), dim3(256), 0, stream, x, pw, pb, off);
    hipLaunchKernelGGL(k_z,      dim3(512),  dim3(256), 0, stream, x, cw, z);
    (void)hipMemsetAsync(gsum, 0, 2 * NOUT * sizeof(float), stream);
    hipLaunchKernelGGL(k_sum,    dim3(4608), dim3(256), 0, stream, off, z, gsum, gsq);
    hipLaunchKernelGGL(k_stats,  dim3(1),    dim3(128), 0, stream, gsum, gsq, gamma, beta, scale, shift);
    hipLaunchKernelGGL(k_apply,  dim3(4608), dim3(256), 0, stream, off, z, scale, shift, out);
}

// Round 5
// 322.209 us; speedup vs baseline: 1.6089x; 1.0206x over previous
//
#include <hip/hip_runtime.h>

#define CIN   64
#define NOUT  128
#define IMH   128
#define IMW   128
#define NPTS  9
#define NB    4
#define HW    (IMH*IMW)          // 16384
#define ROWS  (IMH*NPTS)         // 1152
#define CHS   (ROWS*IMW)         // 147456
#define TOTAL ((size_t)NB*NOUT*CHS)  // 75497472

typedef float f32x4 __attribute__((ext_vector_type(4)));

// ---------------- Kernel A: 3x3 SAME conv, C=64 -> 18 (offsets) ----------------
// Also zeroes the 256-float BN stats region (block 0) to save a memset dispatch.
__global__ __launch_bounds__(256) void k_offset(const float* __restrict__ x,
                                                const float* __restrict__ pw,
                                                const float* __restrict__ pb,
                                                float* __restrict__ off,
                                                float* __restrict__ stats0) {
    __shared__ float wl[576 * 20];        // [c*9+tap][k], stride 20 (float4-aligned)
    __shared__ float red[3 * 64 * 19];    // partials from cg=1..3

    int tid = threadIdx.x;
    if (blockIdx.x == 0) stats0[tid] = 0.f;   // gsum[128] + gsq[128]

    for (int t = tid; t < 18 * 576; t += 256) {
        int k = t / 576, cj = t % 576;    // pw layout [k][c][3][3]
        wl[cj * 20 + k] = pw[t];
    }
    __syncthreads();

    int cg = tid >> 6;        // 0..3 -> channel group
    int lp = tid & 63;        // pixel within block
    int gid = blockIdx.x * 64 + lp;
    int b = gid >> 14;
    int hw = gid & 16383;
    int h = hw >> 7;
    int w = hw & 127;

    float acc[18];
#pragma unroll
    for (int k = 0; k < 18; ++k) acc[k] = (cg == 0) ? pb[k] : 0.f;

    const float* xb = x + (size_t)b * CIN * HW;
    int c0 = cg * 16;
    for (int c = c0; c < c0 + 16; ++c) {
        const float* xc = xb + c * HW;
#pragma unroll
        for (int dh = 0; dh < 3; ++dh) {
            int hh = h + dh - 1;
            if ((unsigned)hh >= 128u) continue;
#pragma unroll
            for (int dw = 0; dw < 3; ++dw) {
                int ww = w + dw - 1;
                if ((unsigned)ww >= 128u) continue;
                float xv = xc[hh * IMW + ww];
                const float* wr = &wl[(c * 9 + dh * 3 + dw) * 20];
                float wv[18];
                *(float4*)&wv[0]  = *(const float4*)(wr);
                *(float4*)&wv[4]  = *(const float4*)(wr + 4);
                *(float4*)&wv[8]  = *(const float4*)(wr + 8);
                *(float4*)&wv[12] = *(const float4*)(wr + 12);
                *(float2*)&wv[16] = *(const float2*)(wr + 16);
#pragma unroll
                for (int k = 0; k < 18; ++k) acc[k] += wv[k] * xv;
            }
        }
    }

    if (cg > 0) {
        float* rp = &red[((cg - 1) * 64 + lp) * 19];
#pragma unroll
        for (int k = 0; k < 18; ++k) rp[k] = acc[k];
    }
    __syncthreads();
    if (cg == 0) {
#pragma unroll
        for (int k = 0; k < 18; ++k)
            acc[k] += red[(0 * 64 + lp) * 19 + k] + red[(64 + lp) * 19 + k] + red[(128 + lp) * 19 + k];
        float* ob = off + (size_t)b * 18 * HW + hw;
#pragma unroll
        for (int k = 0; k < 18; ++k) ob[k * HW] = acc[k];
    }
}

// ---------------- Kernel Z: 1x1 conv, x[b][c][hw] -> z[b][hw][oc] ----------------
__global__ __launch_bounds__(256) void k_z(const float* __restrict__ x,
                                           const float* __restrict__ cw,
                                           float* __restrict__ z) {
    __shared__ float xs[64 * 128];   // [c][hw_local]
    __shared__ float wsm[64 * 128];  // [c][oc]
    int tid = threadIdx.x;
    int b   = blockIdx.x >> 7;
    int hw0 = (blockIdx.x & 127) << 7;

    const float* xb = x + (size_t)b * CIN * HW + hw0;
#pragma unroll
    for (int i = 0; i < 32; ++i) {
        int t = tid + i * 256;
        int c = t >> 7, l = t & 127;
        xs[t] = xb[c * HW + l];
    }
#pragma unroll
    for (int i = 0; i < 32; ++i) {
        int t = tid + i * 256;
        int oc = t & 127, c = t >> 7;        // cw layout [oc][c]
        wsm[c * 128 + oc] = cw[oc * 64 + c];
    }
    __syncthreads();

    int hw4  = (tid & 31) << 2;
    int oc16 = (tid >> 5) << 4;

    float acc[4][16];
#pragma unroll
    for (int j = 0; j < 4; ++j)
#pragma unroll
        for (int k = 0; k < 16; ++k) acc[j][k] = 0.f;

    for (int c = 0; c < 64; ++c) {
        float4 xv = *(const float4*)&xs[c * 128 + hw4];
        float xq[4] = {xv.x, xv.y, xv.z, xv.w};
        float wv[16];
        const float4* wrow = (const float4*)&wsm[c * 128 + oc16];
#pragma unroll
        for (int m = 0; m < 4; ++m) ((float4*)wv)[m] = wrow[m];
#pragma unroll
        for (int j = 0; j < 4; ++j)
#pragma unroll
            for (int k = 0; k < 16; ++k) acc[j][k] += xq[j] * wv[k];
    }

#pragma unroll
    for (int j = 0; j < 4; ++j) {
        size_t rowb = ((size_t)b * HW + hw0 + hw4 + j) * NOUT + oc16;
        float4* zp = (float4*)&z[rowb];
#pragma unroll
        for (int m = 0; m < 4; ++m)
            zp[m] = make_float4(acc[j][4*m], acc[j][4*m+1], acc[j][4*m+2], acc[j][4*m+3]);
    }
}

// ---------------- shared device helper: bilinear coords for one (b,h,n,w) ----------------
__device__ __forceinline__ void bilin_setup(const float* __restrict__ off,
                                            int b, int h, int n, int w,
                                            float4& g, int4& id) {
    const float* ob = off + ((size_t)b * 18 + n) * HW + h * IMW + w;
    float ox = ob[0];
    float oy = ob[9 * HW];
    float px = ox + (float)(n / 3) + (float)h;
    float py = oy + (float)(n % 3) + (float)w;
    float fX = floorf(px), fY = floorf(py);
    float fx = px - fX, fy = py - fY;
    int X = (int)fX, Y = (int)fY;
    g.x = (1.f - fx) * (1.f - fy);   // lt (X,   Y)
    g.y = fx * fy;                   // rb (X+1, Y+1)
    g.z = (1.f - fx) * fy;           // lb (X,   Y+1)
    g.w = fx * (1.f - fy);           // rt (X+1, Y)
    id.x = min(max(X * IMW + Y, 0), HW - 1) * NOUT;
    id.y = min(max((X + 1) * IMW + (Y + 1), 0), HW - 1) * NOUT;
    id.z = min(max(X * IMW + (Y + 1), 0), HW - 1) * NOUT;
    id.w = min(max((X + 1) * IMW + Y, 0), HW - 1) * NOUT;
}

// XCD-aware bijective swizzle: 4608 = 8 XCDs x 576 contiguous logical blocks.
__device__ __forceinline__ int swz_block() {
    return (blockIdx.x & 7) * 576 + (blockIdx.x >> 3);
}

// ---------------- Kernel S: gather pass 1 — BN sums, channel-per-lane, prefetched ----------------
__global__ __launch_bounds__(256) void k_sum(const float* __restrict__ off,
                                             const float* __restrict__ z,
                                             float* __restrict__ gsum,
                                             float* __restrict__ gsq) {
    int logical = swz_block();
    int n  = logical % 9;
    int t2 = logical / 9;
    int h  = t2 & 127;
    int b  = t2 >> 7;

    __shared__ float4 gS[128];
    __shared__ int4   iS[128];
    __shared__ float  lsum[128];
    __shared__ float  lsq[128];

    int tid = threadIdx.x;
    if (tid < 128) {
        lsum[tid] = 0.f; lsq[tid] = 0.f;
        float4 g; int4 id;
        bilin_setup(off, b, h, n, tid, g, id);
        gS[tid] = g; iS[tid] = id;
    }
    __syncthreads();

    int g32 = tid >> 5;              // 0..7: w sub-slot
    int c4  = (tid & 31) << 2;       // 4 consecutive channels
    const float* zb = z + (size_t)b * HW * NOUT + c4;

    float s0=0, s1=0, s2=0, s3=0, q0=0, q1=0, q2=0, q3=0;

    // depth-1 software prefetch: 8 float4 in flight per thread
    float4 plt, prb, plb, prt;
    {
        int4 id = iS[g32];
        plt = *(const float4*)(zb + id.x);
        prb = *(const float4*)(zb + id.y);
        plb = *(const float4*)(zb + id.z);
        prt = *(const float4*)(zb + id.w);
    }
#pragma unroll
    for (int wi = 0; wi < 16; ++wi) {
        float4 nlt, nrb, nlb, nrt;
        if (wi < 15) {
            int4 idn = iS[((wi + 1) << 3) + g32];
            nlt = *(const float4*)(zb + idn.x);
            nrb = *(const float4*)(zb + idn.y);
            nlb = *(const float4*)(zb + idn.z);
            nrt = *(const float4*)(zb + idn.w);
        }
        float4 g = gS[(wi << 3) + g32];
        float a0 = g.x*plt.x + g.y*prb.x + g.z*plb.x + g.w*prt.x;
        float a1 = g.x*plt.y + g.y*prb.y + g.z*plb.y + g.w*prt.y;
        float a2 = g.x*plt.z + g.y*prb.z + g.z*plb.z + g.w*prt.z;
        float a3 = g.x*plt.w + g.y*prb.w + g.z*plb.w + g.w*prt.w;
        s0 += a0; q0 += a0*a0;
        s1 += a1; q1 += a1*a1;
        s2 += a2; q2 += a2*a2;
        s3 += a3; q3 += a3*a3;
        plt = nlt; prb = nrb; plb = nlb; prt = nrt;
    }
    atomicAdd(&lsum[c4],     s0);
    atomicAdd(&lsum[c4 + 1], s1);
    atomicAdd(&lsum[c4 + 2], s2);
    atomicAdd(&lsum[c4 + 3], s3);
    atomicAdd(&lsq[c4],      q0);
    atomicAdd(&lsq[c4 + 1],  q1);
    atomicAdd(&lsq[c4 + 2],  q2);
    atomicAdd(&lsq[c4 + 3],  q3);
    __syncthreads();
    if (tid < 128)       atomicAdd(&gsum[tid],      lsum[tid]);
    else                 atomicAdd(&gsq[tid - 128], lsq[tid - 128]);
}

// ---------------- Kernel M: finalize BN stats -> scale/shift ----------------
__global__ void k_stats(const float* __restrict__ gsum, const float* __restrict__ gsq,
                        const float* __restrict__ gamma, const float* __restrict__ beta,
                        float* __restrict__ scale, float* __restrict__ shift) {
    int c = threadIdx.x;
    const float cnt = (float)(NB * ROWS * IMW);  // 589824
    float m = gsum[c] / cnt;
    float v = gsq[c] / cnt - m * m;
    float inv = rsqrtf(fmaxf(v, 0.f) + 1e-5f);
    float sc = inv * gamma[c];
    scale[c] = sc;
    shift[c] = beta[c] - m * sc;
}

// ---------------- k_apply helpers ----------------
__device__ __forceinline__ void proc_store(float4 vlt, float4 vrb, float4 vlb, float4 vrt,
                                           float4 g, float4 sc, float4 sh,
                                           float* __restrict__ dst) {
    float t0 = (g.x*vlt.x + g.y*vrb.x + g.z*vlb.x + g.w*vrt.x) * sc.x + sh.x;
    float t1 = (g.x*vlt.y + g.y*vrb.y + g.z*vlb.y + g.w*vrt.y) * sc.y + sh.y;
    float t2 = (g.x*vlt.z + g.y*vrb.z + g.z*vlb.z + g.w*vrt.z) * sc.z + sh.z;
    float t3 = (g.x*vlt.w + g.y*vrb.w + g.z*vlb.w + g.w*vrt.w) * sc.w + sh.w;
    float4 y;
    y.x = t0 / (1.f + __expf(-t0));
    y.y = t1 / (1.f + __expf(-t1));
    y.z = t2 / (1.f + __expf(-t2));
    y.w = t3 / (1.f + __expf(-t3));
    *(float4*)dst = y;
}

#define GLOAD(P, wabs) { int4 _id = iS[wabs]; \
    P##lt = *(const float4*)(zb + _id.x); \
    P##rb = *(const float4*)(zb + _id.y); \
    P##lb = *(const float4*)(zb + _id.z); \
    P##rt = *(const float4*)(zb + _id.w); }

// ---------------- Kernel B: gather pass 2 — double-buffered gather + LDS transpose
//                  + BN apply + SiLU + nontemporal coalesced stores ----------------
__global__ __launch_bounds__(256) void k_apply(const float* __restrict__ off,
                                               const float* __restrict__ z,
                                               const float* __restrict__ scale,
                                               const float* __restrict__ shift,
                                               float* __restrict__ out) {
    int logical = swz_block();
    int n  = logical % 9;
    int t2 = logical / 9;
    int h  = t2 & 127;
    int b  = t2 >> 7;

    __shared__ float4 gS[128];
    __shared__ int4   iS[128];
    __shared__ float  ybuf[2][32 * 133];   // stride 133: conflict-free transpose

    int tid = threadIdx.x;
    if (tid < 128) {
        float4 g; int4 id;
        bilin_setup(off, b, h, n, tid, g, id);
        gS[tid] = g; iS[tid] = id;
    }
    __syncthreads();

    int ws = tid >> 5;               // 0..7: w sub-slot
    int c4 = (tid & 31) << 2;        // 4 consecutive channels
    float4 sc = *(const float4*)&scale[c4];
    float4 sh = *(const float4*)&shift[c4];
    const float* zb = z + (size_t)b * HW * NOUT + c4;
    int r = h * 9 + n;
    float* outr = out + (size_t)b * NOUT * CHS + (size_t)r * IMW;

    float4 A0lt, A0rb, A0lb, A0rt;
    float4 A1lt, A1rb, A1lb, A1rt;
    float4 A2lt, A2rb, A2lb, A2rt;
    float4 A3lt, A3rb, A3lb, A3rt;

    // prologue: load + process chunk 0 into buf 0
    GLOAD(A0, ws);       GLOAD(A1, 8 + ws);
    GLOAD(A2, 16 + ws);  GLOAD(A3, 24 + ws);
    proc_store(A0lt,A0rb,A0lb,A0rt, gS[ws],      sc, sh, &ybuf[0][(ws)      * 133 + c4]);
    proc_store(A1lt,A1rb,A1lb,A1rt, gS[8 + ws],  sc, sh, &ybuf[0][(8 + ws)  * 133 + c4]);
    proc_store(A2lt,A2rb,A2lb,A2rt, gS[16 + ws], sc, sh, &ybuf[0][(16 + ws) * 133 + c4]);
    proc_store(A3lt,A3rb,A3lb,A3rt, gS[24 + ws], sc, sh, &ybuf[0][(24 + ws) * 133 + c4]);
    __syncthreads();

#pragma unroll
    for (int chunk = 0; chunk < 4; ++chunk) {
        const int cur = chunk & 1;
        const int nxt = cur ^ 1;
        int w0 = chunk << 5;

        // issue next chunk's gather loads early (latency hides under writeout)
        if (chunk < 3) {
            int wn = w0 + 32;
            GLOAD(A0, wn + ws);       GLOAD(A1, wn + 8 + ws);
            GLOAD(A2, wn + 16 + ws);  GLOAD(A3, wn + 24 + ws);
        }

        // writeout current chunk: LDS transpose, coalesced NT float4 over w
#pragma unroll
        for (int i = 0; i < 4; ++i) {
            int task = (i << 8) + tid;     // 0..1023
            int oc   = task >> 3;
            int w4   = (task & 7) << 2;
            f32x4 v;
            v.x = ybuf[cur][(w4 + 0) * 133 + oc];
            v.y = ybuf[cur][(w4 + 1) * 133 + oc];
            v.z = ybuf[cur][(w4 + 2) * 133 + oc];
            v.w = ybuf[cur][(w4 + 3) * 133 + oc];
            __builtin_nontemporal_store(v, (f32x4*)(outr + (size_t)oc * CHS + w0 + w4));
        }

        // consume staged loads into the other buffer
        if (chunk < 3) {
            int wn = w0 + 32;
            proc_store(A0lt,A0rb,A0lb,A0rt, gS[wn + ws],      sc, sh, &ybuf[nxt][(ws)      * 133 + c4]);
            proc_store(A1lt,A1rb,A1lb,A1rt, gS[wn + 8 + ws],  sc, sh, &ybuf[nxt][(8 + ws)  * 133 + c4]);
            proc_store(A2lt,A2rb,A2lb,A2rt, gS[wn + 16 + ws], sc, sh, &ybuf[nxt][(16 + ws) * 133 + c4]);
            proc_store(A3lt,A3rb,A3lb,A3rt, gS[wn + 24 + ws], sc, sh, &ybuf[nxt][(24 + ws) * 133 + c4]);
        }
        __syncthreads();
    }
}

extern "C" void kernel_launch(void* const* d_in, const int* in_sizes, int n_in,
                              void* d_out, int out_size, void* d_ws, size_t ws_size,
                              hipStream_t stream) {
    const float* x     = (const float*)d_in[0];
    const float* pw    = (const float*)d_in[1];
    const float* pb    = (const float*)d_in[2];
    const float* cw    = (const float*)d_in[3];
    const float* gamma = (const float*)d_in[4];
    const float* beta  = (const float*)d_in[5];
    // d_in[6]/d_in[7] (attn_w/attn_b): dead code in the reference — unused.

    float* out = (float*)d_out;
    float* ws  = (float*)d_ws;

    float* off   = ws;                                   // 4*18*16384
    float* z     = off + (size_t)NB * 18 * HW;           // 4*16384*128
    float* gsum  = z + (size_t)NB * HW * NOUT;           // 128
    float* gsq   = gsum + NOUT;                          // 128
    float* scale = gsq + NOUT;                           // 128
    float* shift = scale + NOUT;                         // 128

    hipLaunchKernelGGL(k_offset, dim3(1024), dim3(256), 0, stream, x, pw, pb, off, gsum);
    hipLaunchKernelGGL(k_z,      dim3(512),  dim3(256), 0, stream, x, cw, z);
    hipLaunchKernelGGL(k_sum,    dim3(4608), dim3(256), 0, stream, off, z, gsum, gsq);
    hipLaunchKernelGGL(k_stats,  dim3(1),    dim3(128), 0, stream, gsum, gsq, gamma, beta, scale, shift);
    hipLaunchKernelGGL(k_apply,  dim3(4608), dim3(256), 0, stream, off, z, scale, shift, out);
}

// Round 6
// 303.447 us; speedup vs baseline: 1.7084x; 1.0618x over previous
//
#include <hip/hip_runtime.h>

#define CIN   64
#define NOUT  128
#define IMH   128
#define IMW   128
#define NPTS  9
#define NB    4
#define HW    (IMH*IMW)          // 16384
#define ROWS  (IMH*NPTS)         // 1152
#define CHS   (ROWS*IMW)         // 147456
#define TOTAL ((size_t)NB*NOUT*CHS)  // 75497472

typedef float f32x4 __attribute__((ext_vector_type(4)));
typedef unsigned short ushort_t;

// fp32 -> bf16 with round-to-nearest-even (normals; matches __float2bfloat16)
__device__ __forceinline__ ushort_t f2bf(float f) {
    union { float f; unsigned u; } a; a.f = f;
    unsigned r = a.u + 0x7FFFu + ((a.u >> 16) & 1u);
    return (ushort_t)(r >> 16);
}

// 8 packed bf16 (uint4) -> 8 fp32
__device__ __forceinline__ void cvt8(uint4 v, float* f) {
    f[0] = __uint_as_float(v.x << 16); f[1] = __uint_as_float(v.x & 0xFFFF0000u);
    f[2] = __uint_as_float(v.y << 16); f[3] = __uint_as_float(v.y & 0xFFFF0000u);
    f[4] = __uint_as_float(v.z << 16); f[5] = __uint_as_float(v.z & 0xFFFF0000u);
    f[6] = __uint_as_float(v.w << 16); f[7] = __uint_as_float(v.w & 0xFFFF0000u);
}

// ---------------- Kernel A: 3x3 SAME conv, C=64 -> 18 (offsets) ----------------
// Block 0 also zeroes the 256-float BN stats region (saves a memset dispatch).
__global__ __launch_bounds__(256) void k_offset(const float* __restrict__ x,
                                                const float* __restrict__ pw,
                                                const float* __restrict__ pb,
                                                float* __restrict__ off,
                                                float* __restrict__ stats0) {
    __shared__ float wl[576 * 20];        // [c*9+tap][k], stride 20 (float4-aligned)
    __shared__ float red[3 * 64 * 19];    // partials from cg=1..3

    int tid = threadIdx.x;
    if (blockIdx.x == 0) stats0[tid] = 0.f;   // gsum[128] + gsq[128]

    for (int t = tid; t < 18 * 576; t += 256) {
        int k = t / 576, cj = t % 576;    // pw layout [k][c][3][3]
        wl[cj * 20 + k] = pw[t];
    }
    __syncthreads();

    int cg = tid >> 6;        // 0..3 -> channel group
    int lp = tid & 63;        // pixel within block
    int gid = blockIdx.x * 64 + lp;
    int b = gid >> 14;
    int hw = gid & 16383;
    int h = hw >> 7;
    int w = hw & 127;

    float acc[18];
#pragma unroll
    for (int k = 0; k < 18; ++k) acc[k] = (cg == 0) ? pb[k] : 0.f;

    const float* xb = x + (size_t)b * CIN * HW;
    int c0 = cg * 16;
    for (int c = c0; c < c0 + 16; ++c) {
        const float* xc = xb + c * HW;
#pragma unroll
        for (int dh = 0; dh < 3; ++dh) {
            int hh = h + dh - 1;
            if ((unsigned)hh >= 128u) continue;
#pragma unroll
            for (int dw = 0; dw < 3; ++dw) {
                int ww = w + dw - 1;
                if ((unsigned)ww >= 128u) continue;
                float xv = xc[hh * IMW + ww];
                const float* wr = &wl[(c * 9 + dh * 3 + dw) * 20];
                float wv[18];
                *(float4*)&wv[0]  = *(const float4*)(wr);
                *(float4*)&wv[4]  = *(const float4*)(wr + 4);
                *(float4*)&wv[8]  = *(const float4*)(wr + 8);
                *(float4*)&wv[12] = *(const float4*)(wr + 12);
                *(float2*)&wv[16] = *(const float2*)(wr + 16);
#pragma unroll
                for (int k = 0; k < 18; ++k) acc[k] += wv[k] * xv;
            }
        }
    }

    if (cg > 0) {
        float* rp = &red[((cg - 1) * 64 + lp) * 19];
#pragma unroll
        for (int k = 0; k < 18; ++k) rp[k] = acc[k];
    }
    __syncthreads();
    if (cg == 0) {
#pragma unroll
        for (int k = 0; k < 18; ++k)
            acc[k] += red[(0 * 64 + lp) * 19 + k] + red[(64 + lp) * 19 + k] + red[(128 + lp) * 19 + k];
        float* ob = off + (size_t)b * 18 * HW + hw;
#pragma unroll
        for (int k = 0; k < 18; ++k) ob[k * HW] = acc[k];
    }
}

// ---------------- Kernel Z: 1x1 conv, x[b][c][hw] -> z[b][hw][oc] (bf16) ----------------
__global__ __launch_bounds__(256) void k_z(const float* __restrict__ x,
                                           const float* __restrict__ cw,
                                           ushort_t* __restrict__ z) {
    __shared__ float xs[64 * 128];   // [c][hw_local]
    __shared__ float wsm[64 * 128];  // [c][oc]
    int tid = threadIdx.x;
    int b   = blockIdx.x >> 7;
    int hw0 = (blockIdx.x & 127) << 7;

    const float* xb = x + (size_t)b * CIN * HW + hw0;
#pragma unroll
    for (int i = 0; i < 32; ++i) {
        int t = tid + i * 256;
        int c = t >> 7, l = t & 127;
        xs[t] = xb[c * HW + l];
    }
#pragma unroll
    for (int i = 0; i < 32; ++i) {
        int t = tid + i * 256;
        int oc = t & 127, c = t >> 7;        // cw layout [oc][c]
        wsm[c * 128 + oc] = cw[oc * 64 + c];
    }
    __syncthreads();

    int hw4  = (tid & 31) << 2;
    int oc16 = (tid >> 5) << 4;

    float acc[4][16];
#pragma unroll
    for (int j = 0; j < 4; ++j)
#pragma unroll
        for (int k = 0; k < 16; ++k) acc[j][k] = 0.f;

    for (int c = 0; c < 64; ++c) {
        float4 xv = *(const float4*)&xs[c * 128 + hw4];
        float xq[4] = {xv.x, xv.y, xv.z, xv.w};
        float wv[16];
        const float4* wrow = (const float4*)&wsm[c * 128 + oc16];
#pragma unroll
        for (int m = 0; m < 4; ++m) ((float4*)wv)[m] = wrow[m];
#pragma unroll
        for (int j = 0; j < 4; ++j)
#pragma unroll
            for (int k = 0; k < 16; ++k) acc[j][k] += xq[j] * wv[k];
    }

#pragma unroll
    for (int j = 0; j < 4; ++j) {
        ushort_t* zr = z + ((size_t)b * HW + hw0 + hw4 + j) * NOUT + oc16;
        union { ushort_t u[16]; uint4 q[2]; } pk;
#pragma unroll
        for (int k = 0; k < 16; ++k) pk.u[k] = f2bf(acc[j][k]);
        *(uint4*)zr       = pk.q[0];
        *(uint4*)(zr + 8) = pk.q[1];
    }
}

// ---------------- shared device helper: bilinear coords for one (b,h,n,w) ----------------
__device__ __forceinline__ void bilin_setup(const float* __restrict__ off,
                                            int b, int h, int n, int w,
                                            float4& g, int4& id) {
    const float* ob = off + ((size_t)b * 18 + n) * HW + h * IMW + w;
    float ox = ob[0];
    float oy = ob[9 * HW];
    float px = ox + (float)(n / 3) + (float)h;
    float py = oy + (float)(n % 3) + (float)w;
    float fX = floorf(px), fY = floorf(py);
    float fx = px - fX, fy = py - fY;
    int X = (int)fX, Y = (int)fY;
    g.x = (1.f - fx) * (1.f - fy);   // lt (X,   Y)
    g.y = fx * fy;                   // rb (X+1, Y+1)
    g.z = (1.f - fx) * fy;           // lb (X,   Y+1)
    g.w = fx * (1.f - fy);           // rt (X+1, Y)
    id.x = min(max(X * IMW + Y, 0), HW - 1) * NOUT;
    id.y = min(max((X + 1) * IMW + (Y + 1), 0), HW - 1) * NOUT;
    id.z = min(max(X * IMW + (Y + 1), 0), HW - 1) * NOUT;
    id.w = min(max((X + 1) * IMW + Y, 0), HW - 1) * NOUT;
}

// XCD-aware bijective swizzle: 4608 = 8 XCDs x 576 contiguous logical blocks.
__device__ __forceinline__ int swz_block() {
    return (blockIdx.x & 7) * 576 + (blockIdx.x >> 3);
}

// ---------------- Kernel S: gather pass 1 — BN sums, 8ch/lane bf16, wave-reduced ----------------
__global__ __launch_bounds__(256) void k_sum(const float* __restrict__ off,
                                             const ushort_t* __restrict__ z,
                                             float* __restrict__ gsum,
                                             float* __restrict__ gsq) {
    int logical = swz_block();
    int n  = logical % 9;
    int t2 = logical / 9;
    int h  = t2 & 127;
    int b  = t2 >> 7;

    __shared__ float4 gS[128];
    __shared__ int4   iS[128];
    __shared__ float  lsum[128];
    __shared__ float  lsq[128];

    int tid = threadIdx.x;
    if (tid < 128) {
        lsum[tid] = 0.f; lsq[tid] = 0.f;
        float4 g; int4 id;
        bilin_setup(off, b, h, n, tid, g, id);
        gS[tid] = g; iS[tid] = id;
    }
    __syncthreads();

    int g16 = tid >> 4;              // 0..15: w sub-slot
    int c8  = (tid & 15) << 3;       // 8 consecutive channels
    const ushort_t* zb = z + (size_t)b * HW * NOUT + c8;

    float s[8], q[8];
#pragma unroll
    for (int k = 0; k < 8; ++k) { s[k] = 0.f; q[k] = 0.f; }

    // depth-1 software prefetch
    uint4 plt, prb, plb, prt;
    {
        int4 id = iS[g16];
        plt = *(const uint4*)(zb + id.x);
        prb = *(const uint4*)(zb + id.y);
        plb = *(const uint4*)(zb + id.z);
        prt = *(const uint4*)(zb + id.w);
    }
#pragma unroll
    for (int wi = 0; wi < 8; ++wi) {
        uint4 nlt, nrb, nlb, nrt;
        if (wi < 7) {
            int4 idn = iS[((wi + 1) << 4) + g16];
            nlt = *(const uint4*)(zb + idn.x);
            nrb = *(const uint4*)(zb + idn.y);
            nlb = *(const uint4*)(zb + idn.z);
            nrt = *(const uint4*)(zb + idn.w);
        }
        float4 g = gS[(wi << 4) + g16];
        float flt[8], frb[8], flb[8], frt[8];
        cvt8(plt, flt); cvt8(prb, frb); cvt8(plb, flb); cvt8(prt, frt);
#pragma unroll
        for (int k = 0; k < 8; ++k) {
            float a = g.x * flt[k] + g.y * frb[k] + g.z * flb[k] + g.w * frt[k];
            s[k] += a; q[k] += a * a;
        }
        plt = nlt; prb = nrb; plb = nlb; prt = nrt;
    }

    // reduce across the 4 w-subgroups within the wave (lanes tid^16, tid^32 share channels)
#pragma unroll
    for (int k = 0; k < 8; ++k) {
        s[k] += __shfl_xor(s[k], 16, 64); s[k] += __shfl_xor(s[k], 32, 64);
        q[k] += __shfl_xor(q[k], 16, 64); q[k] += __shfl_xor(q[k], 32, 64);
    }
    if (((tid >> 4) & 3) == 0) {
#pragma unroll
        for (int k = 0; k < 8; ++k) {
            atomicAdd(&lsum[c8 + k], s[k]);
            atomicAdd(&lsq[c8 + k],  q[k]);
        }
    }
    __syncthreads();
    if (tid < 128)       atomicAdd(&gsum[tid],      lsum[tid]);
    else                 atomicAdd(&gsq[tid - 128], lsq[tid - 128]);
}

// ---------------- k_apply helper: 4 bf16 corners x 8ch -> BN -> SiLU -> LDS ----------------
__device__ __forceinline__ void proc8(const uint4* C, float4 g,
                                      const float* sc, const float* sh,
                                      float* __restrict__ dst) {
    float flt[8], frb[8], flb[8], frt[8];
    cvt8(C[0], flt); cvt8(C[1], frb); cvt8(C[2], flb); cvt8(C[3], frt);
    float o[8];
#pragma unroll
    for (int k = 0; k < 8; ++k) {
        float t = (g.x * flt[k] + g.y * frb[k] + g.z * flb[k] + g.w * frt[k]) * sc[k] + sh[k];
        o[k] = t / (1.f + __expf(-t));
    }
    *(float4*)dst       = *(float4*)&o[0];
    *(float4*)(dst + 4) = *(float4*)&o[4];
}

// ---------------- Kernel B: gather pass 2 — inline stats + dbuf gather + LDS transpose
//                  + BN apply + SiLU + nontemporal coalesced stores ----------------
__global__ __launch_bounds__(256) void k_apply(const float* __restrict__ off,
                                               const ushort_t* __restrict__ z,
                                               const float* __restrict__ gsum,
                                               const float* __restrict__ gsq,
                                               const float* __restrict__ gamma,
                                               const float* __restrict__ beta,
                                               float* __restrict__ out) {
    int logical = swz_block();
    int n  = logical % 9;
    int t2 = logical / 9;
    int h  = t2 & 127;
    int b  = t2 >> 7;

    __shared__ float4 gS[128];
    __shared__ int4   iS[128];
    __shared__ float  scS[128];
    __shared__ float  shS[128];
    __shared__ float  ybuf[2][32 * 133];   // stride 133: conflict-free transpose

    int tid = threadIdx.x;
    if (tid < 128) {
        const float cnt = (float)(NB * ROWS * IMW);  // 589824
        float m  = gsum[tid] / cnt;
        float vv = gsq[tid] / cnt - m * m;
        float inv = rsqrtf(fmaxf(vv, 0.f) + 1e-5f);
        float sc = inv * gamma[tid];
        scS[tid] = sc;
        shS[tid] = beta[tid] - m * sc;
        float4 g; int4 id;
        bilin_setup(off, b, h, n, tid, g, id);
        gS[tid] = g; iS[tid] = id;
    }
    __syncthreads();

    int g16 = tid >> 4;              // 0..15: w sub-slot
    int c8  = (tid & 15) << 3;       // 8 consecutive channels
    float scv[8], shv[8];
    *(float4*)&scv[0] = *(const float4*)&scS[c8];
    *(float4*)&scv[4] = *(const float4*)&scS[c8 + 4];
    *(float4*)&shv[0] = *(const float4*)&shS[c8];
    *(float4*)&shv[4] = *(const float4*)&shS[c8 + 4];

    const ushort_t* zb = z + (size_t)b * HW * NOUT + c8;
    int r = h * 9 + n;
    float* outr = out + (size_t)b * NOUT * CHS + (size_t)r * IMW;

    uint4 A[8];
#define STAGE(wb) { int4 _i0 = iS[(wb) + g16]; int4 _i1 = iS[(wb) + 16 + g16]; \
    A[0] = *(const uint4*)(zb + _i0.x); A[1] = *(const uint4*)(zb + _i0.y); \
    A[2] = *(const uint4*)(zb + _i0.z); A[3] = *(const uint4*)(zb + _i0.w); \
    A[4] = *(const uint4*)(zb + _i1.x); A[5] = *(const uint4*)(zb + _i1.y); \
    A[6] = *(const uint4*)(zb + _i1.z); A[7] = *(const uint4*)(zb + _i1.w); }
#define PROC(wb, bi) { \
    proc8(&A[0], gS[(wb) + g16],      scv, shv, &ybuf[bi][g16 * 133 + c8]); \
    proc8(&A[4], gS[(wb) + 16 + g16], scv, shv, &ybuf[bi][(16 + g16) * 133 + c8]); }

    // prologue: chunk 0 into buf 0
    STAGE(0);
    PROC(0, 0);
    __syncthreads();

#pragma unroll
    for (int chunk = 0; chunk < 4; ++chunk) {
        const int cur = chunk & 1;
        const int nxt = cur ^ 1;
        int w0 = chunk << 5;

        if (chunk < 3) STAGE(w0 + 32);   // issue next chunk's loads early

        // writeout current chunk: LDS transpose, coalesced NT float4 over w
#pragma unroll
        for (int i = 0; i < 4; ++i) {
            int task = (i << 8) + tid;     // 0..1023
            int oc   = task >> 3;
            int w4   = (task & 7) << 2;
            f32x4 v;
            v.x = ybuf[cur][(w4 + 0) * 133 + oc];
            v.y = ybuf[cur][(w4 + 1) * 133 + oc];
            v.z = ybuf[cur][(w4 + 2) * 133 + oc];
            v.w = ybuf[cur][(w4 + 3) * 133 + oc];
            __builtin_nontemporal_store(v, (f32x4*)(outr + (size_t)oc * CHS + w0 + w4));
        }

        if (chunk < 3) PROC(w0 + 32, nxt);
        __syncthreads();
    }
#undef STAGE
#undef PROC
}

extern "C" void kernel_launch(void* const* d_in, const int* in_sizes, int n_in,
                              void* d_out, int out_size, void* d_ws, size_t ws_size,
                              hipStream_t stream) {
    const float* x     = (const float*)d_in[0];
    const float* pw    = (const float*)d_in[1];
    const float* pb    = (const float*)d_in[2];
    const float* cw    = (const float*)d_in[3];
    const float* gamma = (const float*)d_in[4];
    const float* beta  = (const float*)d_in[5];
    // d_in[6]/d_in[7] (attn_w/attn_b): dead code in the reference — unused.

    float* out = (float*)d_out;
    float* ws  = (float*)d_ws;

    float*    off  = ws;                                     // 1,179,648 f  (4.7 MB)
    ushort_t* z    = (ushort_t*)(off + (size_t)NB * 18 * HW);// 8,388,608 bf16 (16.8 MB)
    float*    gsum = (float*)(z + (size_t)NB * HW * NOUT);   // 128 f
    float*    gsq  = gsum + NOUT;                            // 128 f

    hipLaunchKernelGGL(k_offset, dim3(1024), dim3(256), 0, stream, x, pw, pb, off, gsum);
    hipLaunchKernelGGL(k_z,      dim3(512),  dim3(256), 0, stream, x, cw, z);
    hipLaunchKernelGGL(k_sum,    dim3(4608), dim3(256), 0, stream, off, z, gsum, gsq);
    hipLaunchKernelGGL(k_apply,  dim3(4608), dim3(256), 0, stream, off, z, gsum, gsq, gamma, beta, out);
}